// Round 13
// baseline (379.719 us; speedup 1.0000x reference)
//
#include <hip/hip_runtime.h>

// Problem constants (from reference)
constexpr int B   = 4;
constexpr int CF  = 3;    // feat channels
constexpr int CM  = 21;   // mask channels
constexpr int H   = 128;
constexpr int W   = 128;
constexpr int KS  = 7;
constexpr int PAD = 3;
constexpr int CENTER = (KS * KS) / 2;  // 24
constexpr int NNB = KS * KS - 1;       // 48 neighbors
constexpr int NUM_ITER = 10;

constexpr int TILE = 16;
constexpr int TH   = TILE + 2 * PAD;   // 22 (aff-kernel halo tile)
constexpr int TS   = 24;
constexpr int HW   = H * W;

// fuse-2 geometry
constexpr int IN   = TILE + 4 * PAD;   // 28 input halo tile
constexpr int INS  = 30;               // input LDS row stride (even, non-pow2)
constexpr int MD   = 22;               // intermediate (iter t) region
constexpr int MDS  = 24;               // intermediate LDS row stride (even)
constexpr int CPB  = 7;                // channels per block (3 groups)

// ---------------------------------------------------------------------------
// Kernel 1: per-pixel 48-way softmax affinity (validated R4-R11).
// PLANE-major layout (coalesced): aff[((b*48 + n)*H + h)*W + w]
// ---------------------------------------------------------------------------
__global__ __launch_bounds__(256) void aff_kernel(const float* __restrict__ feats,
                                                  float* __restrict__ aff) {
    __shared__ float tile[CF][TH][TS];
    const int tx = threadIdx.x, ty = threadIdx.y;
    const int bx = blockIdx.x * TILE, by = blockIdx.y * TILE;
    const int b  = blockIdx.z;
    const int tid = ty * TILE + tx;

    for (int c = 0; c < CF; ++c) {
        const float* src = feats + (size_t)(b * CF + c) * HW;
        for (int idx = tid; idx < TH * TH; idx += 256) {
            const int r  = idx / TH, cc = idx - r * TH;
            const int gh = min(max(by + r  - PAD, 0), H - 1);
            const int gw = min(max(bx + cc - PAD, 0), W - 1);
            tile[c][r][cc] = src[gh * W + gw];
        }
    }
    __syncthreads();

    float q[CF], inv[CF];
    #pragma unroll
    for (int c = 0; c < CF; ++c) {
        const float* tp = &tile[c][ty][tx];
        q[c] = tp[PAD * TS + PAD];
        float s = 0.f, s2 = 0.f;
        #pragma unroll
        for (int i = 0; i < KS; ++i)
            #pragma unroll
            for (int j = 0; j < KS; ++j) {
                if (i == PAD && j == PAD) continue;
                const float v = tp[i * TS + j];
                s += v; s2 += v * v;
            }
        const float mean = s * (1.0f / NNB);
        const float var  = fmaxf(s2 - (float)NNB * mean * mean, 0.f) * (1.0f / (NNB - 1));
        inv[c] = 1.0f / (1e-8f + 0.1f * sqrtf(var));
    }

    float a[NNB];
    float mx = -1e30f;
    #pragma unroll
    for (int i = 0; i < KS; ++i)
        #pragma unroll
        for (int j = 0; j < KS; ++j) {
            const int nn = i * KS + j;
            if (nn == CENTER) continue;
            const int n = (nn < CENTER) ? nn : nn - 1;
            float t = 0.f;
            #pragma unroll
            for (int c = 0; c < CF; ++c)
                t += fabsf(tile[c][ty + i][tx + j] - q[c]) * inv[c];
            a[n] = -t * (1.0f / CF);
            mx = fmaxf(mx, a[n]);
        }
    float ssum = 0.f;
    #pragma unroll
    for (int n = 0; n < NNB; ++n) { a[n] = __expf(a[n] - mx); ssum += a[n]; }
    const float rs = 1.0f / ssum;

    const int h = by + ty, w = bx + tx;
    #pragma unroll
    for (int n = 0; n < NNB; ++n)
        aff[(((size_t)b * NNB + n) * H + h) * W + w] = a[n] * rs;
}

// ---------------------------------------------------------------------------
// Kernel 2: TWO fused iterations, pixel-PAIR b64 taps, plane-major aff.
// Pass1: 242 pair-threads compute the 22x22 mid region (iter t) into LDS.
// Pass2: 128 pairs x channel-split {4,3} -> all 256 threads active.
// Pair window-col union = 8 words at even LDS offset -> 4 aligned ds_read_b64.
// ---------------------------------------------------------------------------
__global__ __launch_bounds__(256, 3) void fuse2_kernel(const float* __restrict__ mi,
                                                       const float* __restrict__ aff,
                                                       float* __restrict__ mo) {
    __shared__ float in_t[CPB][IN][INS];   // 23.0 KB
    __shared__ float mid_t[CPB][MD][MDS];  // 14.8 KB

    const int tx = threadIdx.x, ty = threadIdx.y;
    const int tid = ty * TILE + tx;
    const int bx = blockIdx.x * TILE, by = blockIdx.y * TILE;
    const int zz = blockIdx.z;
    const int b  = zz / 3, g = zz % 3;
    const int c0 = g * CPB;

    const float* ab = aff + (size_t)b * NNB * HW;

    // ---- pass-1 pair geometry + aff preload (issued before staging: overlap)
    const bool p1 = tid < 242;
    int r = 0, qp = 0, gh = 0, gw0 = 0, gw1 = 0; bool fast = false;
    float a0[NNB], a1[NNB];
    if (p1) {
        r  = tid / 11; qp = tid - r * 11;            // mid row, col-pair
        gh  = min(max(by - PAD + r, 0), H - 1);
        gw0 = min(max(bx - PAD + 2 * qp,     0), W - 1);
        gw1 = min(max(bx - PAD + 2 * qp + 1, 0), W - 1);
        fast = (gw0 == bx - PAD + 2 * qp) && (gw1 == gw0 + 1);
        const float* a0p = ab + (size_t)gh * W + gw0;
        const float* a1p = ab + (size_t)gh * W + gw1;
        #pragma unroll
        for (int n = 0; n < NNB; ++n) {
            a0[n] = a0p[(size_t)n * HW];
            a1[n] = a1p[(size_t)n * HW];
        }
    }

    // ---- stage 28x28 x 7ch input halo (edge-clamped)
    {
        const float* src = mi + (size_t)(b * CM + c0) * HW;
        for (int s = tid; s < IN * IN; s += 256) {
            const int rr = s / IN, qq = s - rr * IN;
            const int ih = min(max(by - 2 * PAD + rr, 0), H - 1);
            const int iw = min(max(bx - 2 * PAD + qq, 0), W - 1);
            const int go = ih * W + iw;
            #pragma unroll
            for (int c = 0; c < CPB; ++c)
                in_t[c][rr][qq] = src[c * HW + go];
        }
    }
    __syncthreads();

    // ---- pass 1: iteration t on mid 22x22 (column pairs)
    if (p1) {
        const int ar0 = gh - by + PAD;          // tile row of window top (i=0)
        if (fast) {
            const int wl = 2 * qp;              // window col base (EVEN)
            #pragma unroll
            for (int c = 0; c < CPB; ++c) {
                float s0 = 0.f, s1 = 0.f;
                #pragma unroll
                for (int i = 0; i < KS; ++i) {
                    const float* rp = &in_t[c][ar0 + i][wl];
                    const float2 d0 = *(const float2*)rp;
                    const float2 d1 = *(const float2*)(rp + 2);
                    const float2 d2 = *(const float2*)(rp + 4);
                    const float2 d3 = *(const float2*)(rp + 6);
                    const float wv[8] = { d0.x, d0.y, d1.x, d1.y, d2.x, d2.y, d3.x, d3.y };
                    #pragma unroll
                    for (int j = 0; j < KS; ++j) {
                        const int nn = i * KS + j;
                        if (nn == CENTER) continue;
                        const int n = (nn < CENTER) ? nn : nn - 1;
                        s0 += a0[n] * wv[j];
                        s1 += a1[n] * wv[j + 1];
                    }
                }
                *(float2*)&mid_t[c][r][2 * qp] = make_float2(s0, s1);
            }
        } else {                                 // x-edge-clamped pairs only
            const int wl0 = gw0 - bx + PAD, wl1 = gw1 - bx + PAD;
            #pragma unroll
            for (int c = 0; c < CPB; ++c) {
                float s0 = 0.f, s1 = 0.f;
                #pragma unroll
                for (int i = 0; i < KS; ++i) {
                    const float* rp = &in_t[c][ar0 + i][0];
                    #pragma unroll
                    for (int j = 0; j < KS; ++j) {
                        const int nn = i * KS + j;
                        if (nn == CENTER) continue;
                        const int n = (nn < CENTER) ? nn : nn - 1;
                        s0 += a0[n] * rp[wl0 + j];
                        s1 += a1[n] * rp[wl1 + j];
                    }
                }
                *(float2*)&mid_t[c][r][2 * qp] = make_float2(s0, s1);
            }
        }
    }
    __syncthreads();

    // ---- pass 2: iteration t+1, 128 pairs x ch-split {4,3}; all threads active
    {
        const int half = tid >> 7;              // wave-uniform
        const int p    = tid & 127;
        const int trow = p >> 3, tcol = p & 7;
        const int oh = by + trow, ow = bx + 2 * tcol;   // ow EVEN

        float2 bb[NNB];
        {
            const float* a2p = ab + (size_t)oh * W + ow;
            #pragma unroll
            for (int n = 0; n < NNB; ++n)
                bb[n] = *(const float2*)(a2p + (size_t)n * HW);
        }

        const int cc0 = half ? 4 : 0;
        const int ccn = half ? 3 : 4;
        float* dp = mo + (size_t)(b * CM + c0) * HW + (size_t)oh * W + ow;
        for (int k = 0; k < ccn; ++k) {          // wave-uniform trip count
            const int c = cc0 + k;
            float s0 = 0.f, s1 = 0.f;
            #pragma unroll
            for (int i = 0; i < KS; ++i) {
                const float* rp = &mid_t[c][trow + i][2 * tcol];
                const float2 d0 = *(const float2*)rp;
                const float2 d1 = *(const float2*)(rp + 2);
                const float2 d2 = *(const float2*)(rp + 4);
                const float2 d3 = *(const float2*)(rp + 6);
                const float wv[8] = { d0.x, d0.y, d1.x, d1.y, d2.x, d2.y, d3.x, d3.y };
                #pragma unroll
                for (int j = 0; j < KS; ++j) {
                    const int nn = i * KS + j;
                    if (nn == CENTER) continue;
                    const int n = (nn < CENTER) ? nn : nn - 1;
                    s0 += bb[n].x * wv[j];
                    s1 += bb[n].y * wv[j + 1];
                }
            }
            *(float2*)(dp + (size_t)c * HW) = make_float2(s0, s1);
        }
    }
}

// ---------------------------------------------------------------------------
extern "C" void kernel_launch(void* const* d_in, const int* in_sizes, int n_in,
                              void* d_out, int out_size, void* d_ws, size_t ws_size,
                              hipStream_t stream) {
    const float* feats = (const float*)d_in[0];
    const float* mask  = (const float*)d_in[1];
    float* out = (float*)d_out;

    float* aff  = (float*)d_ws;                               // 12.58 MB (plane-major)
    float* buf0 = aff  + (size_t)B * NNB * HW;                // 5.5 MB
    float* buf1 = buf0 + (size_t)B * CM  * HW;                // 5.5 MB

    aff_kernel<<<dim3(W / TILE, H / TILE, B), dim3(TILE, TILE), 0, stream>>>(feats, aff);

    // 5 fused kernels = 10 iterations; last lands in d_out
    dim3 grid(W / TILE, H / TILE, B * 3);
    dim3 blk(TILE, TILE);
    fuse2_kernel<<<grid, blk, 0, stream>>>(mask, aff, buf0);
    fuse2_kernel<<<grid, blk, 0, stream>>>(buf0, aff, buf1);
    fuse2_kernel<<<grid, blk, 0, stream>>>(buf1, aff, buf0);
    fuse2_kernel<<<grid, blk, 0, stream>>>(buf0, aff, buf1);
    fuse2_kernel<<<grid, blk, 0, stream>>>(buf1, aff, out);
}

// Round 14
// 287.509 us; speedup vs baseline: 1.3207x; 1.3207x over previous
//
#include <hip/hip_runtime.h>

// Problem constants (from reference)
constexpr int B   = 4;
constexpr int CF  = 3;    // feat channels
constexpr int CM  = 21;   // mask channels
constexpr int H   = 128;
constexpr int W   = 128;
constexpr int KS  = 7;
constexpr int PAD = 3;
constexpr int CENTER = (KS * KS) / 2;  // 24
constexpr int NNB = KS * KS - 1;       // 48 neighbors
constexpr int NUM_ITER = 10;

constexpr int TILE = 16;
constexpr int TH   = TILE + 2 * PAD;   // 22 (aff-kernel halo tile)
constexpr int TS   = 24;
constexpr int HW   = H * W;

// fuse-2 geometry
constexpr int IN   = TILE + 4 * PAD;   // 28 input halo tile
constexpr int INS  = 30;               // input LDS row stride (even, non-pow2)
constexpr int MD   = 22;               // intermediate (iter t) region
constexpr int MDS  = 24;               // intermediate LDS row stride (even)
constexpr int CPB  = 7;                // channels per block (3 groups)

// ---------------------------------------------------------------------------
// Kernel 1: per-pixel 48-way softmax affinity (validated R4-R13).
// PLANE-major layout (coalesced): aff[((b*48 + n)*H + h)*W + w]
// ---------------------------------------------------------------------------
__global__ __launch_bounds__(256) void aff_kernel(const float* __restrict__ feats,
                                                  float* __restrict__ aff) {
    __shared__ float tile[CF][TH][TS];
    const int tx = threadIdx.x, ty = threadIdx.y;
    const int bx = blockIdx.x * TILE, by = blockIdx.y * TILE;
    const int b  = blockIdx.z;
    const int tid = ty * TILE + tx;

    for (int c = 0; c < CF; ++c) {
        const float* src = feats + (size_t)(b * CF + c) * HW;
        for (int idx = tid; idx < TH * TH; idx += 256) {
            const int r  = idx / TH, cc = idx - r * TH;
            const int gh = min(max(by + r  - PAD, 0), H - 1);
            const int gw = min(max(bx + cc - PAD, 0), W - 1);
            tile[c][r][cc] = src[gh * W + gw];
        }
    }
    __syncthreads();

    float q[CF], inv[CF];
    #pragma unroll
    for (int c = 0; c < CF; ++c) {
        const float* tp = &tile[c][ty][tx];
        q[c] = tp[PAD * TS + PAD];
        float s = 0.f, s2 = 0.f;
        #pragma unroll
        for (int i = 0; i < KS; ++i)
            #pragma unroll
            for (int j = 0; j < KS; ++j) {
                if (i == PAD && j == PAD) continue;
                const float v = tp[i * TS + j];
                s += v; s2 += v * v;
            }
        const float mean = s * (1.0f / NNB);
        const float var  = fmaxf(s2 - (float)NNB * mean * mean, 0.f) * (1.0f / (NNB - 1));
        inv[c] = 1.0f / (1e-8f + 0.1f * sqrtf(var));
    }

    float a[NNB];
    float mx = -1e30f;
    #pragma unroll
    for (int i = 0; i < KS; ++i)
        #pragma unroll
        for (int j = 0; j < KS; ++j) {
            const int nn = i * KS + j;
            if (nn == CENTER) continue;
            const int n = (nn < CENTER) ? nn : nn - 1;
            float t = 0.f;
            #pragma unroll
            for (int c = 0; c < CF; ++c)
                t += fabsf(tile[c][ty + i][tx + j] - q[c]) * inv[c];
            a[n] = -t * (1.0f / CF);
            mx = fmaxf(mx, a[n]);
        }
    float ssum = 0.f;
    #pragma unroll
    for (int n = 0; n < NNB; ++n) { a[n] = __expf(a[n] - mx); ssum += a[n]; }
    const float rs = 1.0f / ssum;

    const int h = by + ty, w = bx + tx;
    #pragma unroll
    for (int n = 0; n < NNB; ++n)
        aff[(((size_t)b * NNB + n) * H + h) * W + w] = a[n] * rs;
}

// ---------------------------------------------------------------------------
// Kernel 2: TWO fused iterations, pixel-PAIR b64 taps, plane-major aff.
// ANTI-SPILL (R13 fix): pass-1 aff arrays initialized UNCONDITIONALLY
// (tid clamped to 241) so SROA promotes them; __launch_bounds__(256,2)
// gives the allocator a 256-VGPR budget (2 blocks/CU, the natural step).
// ---------------------------------------------------------------------------
__global__ __launch_bounds__(256, 2) void fuse2_kernel(const float* __restrict__ mi,
                                                       const float* __restrict__ aff,
                                                       float* __restrict__ mo) {
    __shared__ float in_t[CPB][IN][INS];   // 23.0 KB
    __shared__ float mid_t[CPB][MD][MDS];  // 14.8 KB

    const int tx = threadIdx.x, ty = threadIdx.y;
    const int tid = ty * TILE + tx;
    const int bx = blockIdx.x * TILE, by = blockIdx.y * TILE;
    const int zz = blockIdx.z;
    const int b  = zz / 3, g = zz % 3;
    const int c0 = g * CPB;

    const float* ab = aff + (size_t)b * NNB * HW;

    // ---- pass-1 pair geometry + aff preload, UNCONDITIONAL (spill fix)
    const int  t2 = min(tid, 241);
    const int  r  = t2 / 11, qp = t2 - r * 11;       // mid row, col-pair
    const int  gh  = min(max(by - PAD + r, 0), H - 1);
    const int  gw0 = min(max(bx - PAD + 2 * qp,     0), W - 1);
    const int  gw1 = min(max(bx - PAD + 2 * qp + 1, 0), W - 1);
    const bool fast = (gw0 == bx - PAD + 2 * qp) && (gw1 == gw0 + 1);
    float a0[NNB], a1[NNB];
    {
        const float* a0p = ab + (size_t)gh * W + gw0;
        const float* a1p = ab + (size_t)gh * W + gw1;
        #pragma unroll
        for (int n = 0; n < NNB; ++n) {
            a0[n] = a0p[(size_t)n * HW];
            a1[n] = a1p[(size_t)n * HW];
        }
    }

    // ---- stage 28x28 x 7ch input halo (edge-clamped)
    {
        const float* src = mi + (size_t)(b * CM + c0) * HW;
        for (int s = tid; s < IN * IN; s += 256) {
            const int rr = s / IN, qq = s - rr * IN;
            const int ih = min(max(by - 2 * PAD + rr, 0), H - 1);
            const int iw = min(max(bx - 2 * PAD + qq, 0), W - 1);
            const int go = ih * W + iw;
            #pragma unroll
            for (int c = 0; c < CPB; ++c)
                in_t[c][rr][qq] = src[c * HW + go];
        }
    }
    __syncthreads();

    // ---- pass 1: iteration t on mid 22x22 (column pairs); only tid<242 write
    if (tid < 242) {
        const int ar0 = gh - by + PAD;          // tile row of window top (i=0)
        if (fast) {
            const int wl = 2 * qp;              // window col base (EVEN)
            #pragma unroll
            for (int c = 0; c < CPB; ++c) {
                float s0 = 0.f, s1 = 0.f;
                #pragma unroll
                for (int i = 0; i < KS; ++i) {
                    const float* rp = &in_t[c][ar0 + i][wl];
                    const float2 d0 = *(const float2*)rp;
                    const float2 d1 = *(const float2*)(rp + 2);
                    const float2 d2 = *(const float2*)(rp + 4);
                    const float2 d3 = *(const float2*)(rp + 6);
                    const float wv[8] = { d0.x, d0.y, d1.x, d1.y, d2.x, d2.y, d3.x, d3.y };
                    #pragma unroll
                    for (int j = 0; j < KS; ++j) {
                        const int nn = i * KS + j;
                        if (nn == CENTER) continue;
                        const int n = (nn < CENTER) ? nn : nn - 1;
                        s0 += a0[n] * wv[j];
                        s1 += a1[n] * wv[j + 1];
                    }
                }
                *(float2*)&mid_t[c][r][2 * qp] = make_float2(s0, s1);
            }
        } else {                                 // x-edge-clamped pairs only
            const int wl0 = gw0 - bx + PAD, wl1 = gw1 - bx + PAD;
            #pragma unroll
            for (int c = 0; c < CPB; ++c) {
                float s0 = 0.f, s1 = 0.f;
                #pragma unroll
                for (int i = 0; i < KS; ++i) {
                    const float* rp = &in_t[c][ar0 + i][0];
                    #pragma unroll
                    for (int j = 0; j < KS; ++j) {
                        const int nn = i * KS + j;
                        if (nn == CENTER) continue;
                        const int n = (nn < CENTER) ? nn : nn - 1;
                        s0 += a0[n] * rp[wl0 + j];
                        s1 += a1[n] * rp[wl1 + j];
                    }
                }
                *(float2*)&mid_t[c][r][2 * qp] = make_float2(s0, s1);
            }
        }
    }
    __syncthreads();

    // ---- pass 2: iteration t+1, 128 pairs x ch-split {4,3}; all threads active
    {
        const int half = tid >> 7;              // wave-uniform
        const int p    = tid & 127;
        const int trow = p >> 3, tcol = p & 7;
        const int oh = by + trow, ow = bx + 2 * tcol;   // ow EVEN

        float2 bb[NNB];
        {
            const float* a2p = ab + (size_t)oh * W + ow;
            #pragma unroll
            for (int n = 0; n < NNB; ++n)
                bb[n] = *(const float2*)(a2p + (size_t)n * HW);
        }

        const int cc0 = half ? 4 : 0;
        const int ccn = half ? 3 : 4;
        float* dp = mo + (size_t)(b * CM + c0) * HW + (size_t)oh * W + ow;
        for (int k = 0; k < ccn; ++k) {          // wave-uniform trip count
            const int c = cc0 + k;
            float s0 = 0.f, s1 = 0.f;
            #pragma unroll
            for (int i = 0; i < KS; ++i) {
                const float* rp = &mid_t[c][trow + i][2 * tcol];
                const float2 d0 = *(const float2*)rp;
                const float2 d1 = *(const float2*)(rp + 2);
                const float2 d2 = *(const float2*)(rp + 4);
                const float2 d3 = *(const float2*)(rp + 6);
                const float wv[8] = { d0.x, d0.y, d1.x, d1.y, d2.x, d2.y, d3.x, d3.y };
                #pragma unroll
                for (int j = 0; j < KS; ++j) {
                    const int nn = i * KS + j;
                    if (nn == CENTER) continue;
                    const int n = (nn < CENTER) ? nn : nn - 1;
                    s0 += bb[n].x * wv[j];
                    s1 += bb[n].y * wv[j + 1];
                }
            }
            *(float2*)(dp + (size_t)c * HW) = make_float2(s0, s1);
        }
    }
}

// ---------------------------------------------------------------------------
extern "C" void kernel_launch(void* const* d_in, const int* in_sizes, int n_in,
                              void* d_out, int out_size, void* d_ws, size_t ws_size,
                              hipStream_t stream) {
    const float* feats = (const float*)d_in[0];
    const float* mask  = (const float*)d_in[1];
    float* out = (float*)d_out;

    float* aff  = (float*)d_ws;                               // 12.58 MB (plane-major)
    float* buf0 = aff  + (size_t)B * NNB * HW;                // 5.5 MB
    float* buf1 = buf0 + (size_t)B * CM  * HW;                // 5.5 MB

    aff_kernel<<<dim3(W / TILE, H / TILE, B), dim3(TILE, TILE), 0, stream>>>(feats, aff);

    // 5 fused kernels = 10 iterations; last lands in d_out
    dim3 grid(W / TILE, H / TILE, B * 3);
    dim3 blk(TILE, TILE);
    fuse2_kernel<<<grid, blk, 0, stream>>>(mask, aff, buf0);
    fuse2_kernel<<<grid, blk, 0, stream>>>(buf0, aff, buf1);
    fuse2_kernel<<<grid, blk, 0, stream>>>(buf1, aff, buf0);
    fuse2_kernel<<<grid, blk, 0, stream>>>(buf0, aff, buf1);
    fuse2_kernel<<<grid, blk, 0, stream>>>(buf1, aff, out);
}

// Round 15
// 162.956 us; speedup vs baseline: 2.3302x; 1.7643x over previous
//
#include <hip/hip_runtime.h>

// Problem constants (from reference)
constexpr int B   = 4;
constexpr int CF  = 3;    // feat channels
constexpr int CM  = 21;   // mask channels
constexpr int H   = 128;
constexpr int W   = 128;
constexpr int KS  = 7;
constexpr int PAD = 3;
constexpr int CENTER = (KS * KS) / 2;  // 24
constexpr int NNB = KS * KS - 1;       // 48 neighbors
constexpr int NUM_ITER = 10;

constexpr int TILE = 16;
constexpr int TH   = TILE + 2 * PAD;   // 22 (aff-kernel halo tile)
constexpr int TS   = 24;
constexpr int HW   = H * W;

// fuse-2 geometry
constexpr int IN   = TILE + 4 * PAD;   // 28 input halo tile
constexpr int INS  = 30;               // input LDS row stride
constexpr int MD   = 22;               // intermediate (iter t) region
constexpr int MDS  = 24;               // intermediate LDS row stride
constexpr int CPB  = 7;                // channels per block (3 groups)
constexpr int NMID = MD * MD;          // 484 mid pixels

// ---------------------------------------------------------------------------
// Kernel 1: per-pixel 48-way softmax affinity (validated R4-R14).
// PLANE-major layout (coalesced): aff[((b*48 + n)*H + h)*W + w]
// ---------------------------------------------------------------------------
__global__ __launch_bounds__(256) void aff_kernel(const float* __restrict__ feats,
                                                  float* __restrict__ aff) {
    __shared__ float tile[CF][TH][TS];
    const int tx = threadIdx.x, ty = threadIdx.y;
    const int bx = blockIdx.x * TILE, by = blockIdx.y * TILE;
    const int b  = blockIdx.z;
    const int tid = ty * TILE + tx;

    for (int c = 0; c < CF; ++c) {
        const float* src = feats + (size_t)(b * CF + c) * HW;
        for (int idx = tid; idx < TH * TH; idx += 256) {
            const int r  = idx / TH, cc = idx - r * TH;
            const int gh = min(max(by + r  - PAD, 0), H - 1);
            const int gw = min(max(bx + cc - PAD, 0), W - 1);
            tile[c][r][cc] = src[gh * W + gw];
        }
    }
    __syncthreads();

    float q[CF], inv[CF];
    #pragma unroll
    for (int c = 0; c < CF; ++c) {
        const float* tp = &tile[c][ty][tx];
        q[c] = tp[PAD * TS + PAD];
        float s = 0.f, s2 = 0.f;
        #pragma unroll
        for (int i = 0; i < KS; ++i)
            #pragma unroll
            for (int j = 0; j < KS; ++j) {
                if (i == PAD && j == PAD) continue;
                const float v = tp[i * TS + j];
                s += v; s2 += v * v;
            }
        const float mean = s * (1.0f / NNB);
        const float var  = fmaxf(s2 - (float)NNB * mean * mean, 0.f) * (1.0f / (NNB - 1));
        inv[c] = 1.0f / (1e-8f + 0.1f * sqrtf(var));
    }

    float a[NNB];
    float mx = -1e30f;
    #pragma unroll
    for (int i = 0; i < KS; ++i)
        #pragma unroll
        for (int j = 0; j < KS; ++j) {
            const int nn = i * KS + j;
            if (nn == CENTER) continue;
            const int n = (nn < CENTER) ? nn : nn - 1;
            float t = 0.f;
            #pragma unroll
            for (int c = 0; c < CF; ++c)
                t += fabsf(tile[c][ty + i][tx + j] - q[c]) * inv[c];
            a[n] = -t * (1.0f / CF);
            mx = fmaxf(mx, a[n]);
        }
    float ssum = 0.f;
    #pragma unroll
    for (int n = 0; n < NNB; ++n) { a[n] = __expf(a[n] - mx); ssum += a[n]; }
    const float rs = 1.0f / ssum;

    const int h = by + ty, w = bx + tx;
    #pragma unroll
    for (int n = 0; n < NNB; ++n)
        aff[(((size_t)b * NNB + n) * H + h) * W + w] = a[n] * rs;
}

// ---------------------------------------------------------------------------
// Kernel 2: TWO fused iterations — SPILL-PROOF version.
// Exactly ONE a[48] aff array per thread, always unconditionally initialized
// (clamped geometry), reloaded for each of: mid sweep 1, mid sweep 2, pass 2.
// Only LDS/global STORES are predicated. Scalar b32 taps (compiler -> read2).
// ---------------------------------------------------------------------------
__global__ __launch_bounds__(256, 2) void fuse2_kernel(const float* __restrict__ mi,
                                                       const float* __restrict__ aff,
                                                       float* __restrict__ mo) {
    __shared__ float in_t[CPB][IN][INS];   // 23.0 KB
    __shared__ float mid_t[CPB][MD][MDS];  // 14.8 KB

    const int tx = threadIdx.x, ty = threadIdx.y;
    const int tid = ty * TILE + tx;
    const int bx = blockIdx.x * TILE, by = blockIdx.y * TILE;
    const int zz = blockIdx.z;
    const int b  = zz / 3, g = zz % 3;
    const int c0 = g * CPB;

    const float* ab = aff + (size_t)b * NNB * HW;

    // ---- sweep-1 geometry (mid pixel m = tid; always < 484) + aff preload
    const int r1 = tid / MD, q1 = tid - r1 * MD;
    const int gh1 = min(max(by - PAD + r1, 0), H - 1);
    const int gw1 = min(max(bx - PAD + q1, 0), W - 1);

    float a[NNB];
    {
        const float* ap = ab + (size_t)gh1 * W + gw1;
        #pragma unroll
        for (int n = 0; n < NNB; ++n) a[n] = ap[(size_t)n * HW];
    }

    // ---- stage 28x28 x 7ch input halo (edge-clamped)
    {
        const float* src = mi + (size_t)(b * CM + c0) * HW;
        for (int s = tid; s < IN * IN; s += 256) {
            const int rr = s / IN, qq = s - rr * IN;
            const int ih = min(max(by - 2 * PAD + rr, 0), H - 1);
            const int iw = min(max(bx - 2 * PAD + qq, 0), W - 1);
            const int go = ih * W + iw;
            #pragma unroll
            for (int c = 0; c < CPB; ++c)
                in_t[c][rr][qq] = src[c * HW + go];
        }
    }
    __syncthreads();

    // ---- pass 1, sweep 1: iteration t at mid pixel tid (all 256 threads)
    {
        const int ar = gh1 - by + PAD;   // window top row in in_t
        const int ac = gw1 - bx + PAD;   // window left col in in_t
        #pragma unroll
        for (int c = 0; c < CPB; ++c) {
            const float* tp = &in_t[c][ar][ac];
            float s = 0.f;
            #pragma unroll
            for (int i = 0; i < KS; ++i)
                #pragma unroll
                for (int j = 0; j < KS; ++j) {
                    const int nn = i * KS + j;
                    if (nn == CENTER) continue;
                    const int n = (nn < CENTER) ? nn : nn - 1;
                    s += a[n] * tp[i * INS + j];
                }
            mid_t[c][r1][q1] = s;
        }
    }

    // ---- pass 1, sweep 2: mid pixel tid+256 (clamped; store predicated)
    {
        const int m2 = (tid + 256 < NMID) ? tid + 256 : NMID - 1;
        const int r2 = m2 / MD, q2 = m2 - r2 * MD;
        const int gh2 = min(max(by - PAD + r2, 0), H - 1);
        const int gw2 = min(max(bx - PAD + q2, 0), W - 1);
        {
            const float* ap = ab + (size_t)gh2 * W + gw2;
            #pragma unroll
            for (int n = 0; n < NNB; ++n) a[n] = ap[(size_t)n * HW];
        }
        const int ar = gh2 - by + PAD;
        const int ac = gw2 - bx + PAD;
        const bool wr = (tid + 256 < NMID);
        #pragma unroll
        for (int c = 0; c < CPB; ++c) {
            const float* tp = &in_t[c][ar][ac];
            float s = 0.f;
            #pragma unroll
            for (int i = 0; i < KS; ++i)
                #pragma unroll
                for (int j = 0; j < KS; ++j) {
                    const int nn = i * KS + j;
                    if (nn == CENTER) continue;
                    const int n = (nn < CENTER) ? nn : nn - 1;
                    s += a[n] * tp[i * INS + j];
                }
            if (wr) mid_t[c][r2][q2] = s;
        }
    }
    __syncthreads();

    // ---- pass 2: iteration t+1 at own output pixel (reload a[48])
    {
        const int oh = by + ty, ow = bx + tx;
        {
            const float* ap = ab + (size_t)oh * W + ow;
            #pragma unroll
            for (int n = 0; n < NNB; ++n) a[n] = ap[(size_t)n * HW];
        }
        float* dp = mo + (size_t)(b * CM + c0) * HW + (size_t)oh * W + ow;
        #pragma unroll
        for (int c = 0; c < CPB; ++c) {
            const float* tp = &mid_t[c][ty][tx];
            float s = 0.f;
            #pragma unroll
            for (int i = 0; i < KS; ++i)
                #pragma unroll
                for (int j = 0; j < KS; ++j) {
                    const int nn = i * KS + j;
                    if (nn == CENTER) continue;
                    const int n = (nn < CENTER) ? nn : nn - 1;
                    s += a[n] * tp[i * MDS + j];
                }
            dp[(size_t)c * HW] = s;
        }
    }
}

// ---------------------------------------------------------------------------
extern "C" void kernel_launch(void* const* d_in, const int* in_sizes, int n_in,
                              void* d_out, int out_size, void* d_ws, size_t ws_size,
                              hipStream_t stream) {
    const float* feats = (const float*)d_in[0];
    const float* mask  = (const float*)d_in[1];
    float* out = (float*)d_out;

    float* aff  = (float*)d_ws;                               // 12.58 MB (plane-major)
    float* buf0 = aff  + (size_t)B * NNB * HW;                // 5.5 MB
    float* buf1 = buf0 + (size_t)B * CM  * HW;                // 5.5 MB

    aff_kernel<<<dim3(W / TILE, H / TILE, B), dim3(TILE, TILE), 0, stream>>>(feats, aff);

    // 5 fused kernels = 10 iterations; last lands in d_out
    dim3 grid(W / TILE, H / TILE, B * 3);
    dim3 blk(TILE, TILE);
    fuse2_kernel<<<grid, blk, 0, stream>>>(mask, aff, buf0);
    fuse2_kernel<<<grid, blk, 0, stream>>>(buf0, aff, buf1);
    fuse2_kernel<<<grid, blk, 0, stream>>>(buf1, aff, buf0);
    fuse2_kernel<<<grid, blk, 0, stream>>>(buf0, aff, buf1);
    fuse2_kernel<<<grid, blk, 0, stream>>>(buf1, aff, out);
}